// Round 10
// baseline (531.010 us; speedup 1.0000x reference)
//
#include <hip/hip_runtime.h>
#include <hip/hip_bf16.h>
#include <stdint.h>

typedef unsigned short u16;
typedef __bf16 bf16x8 __attribute__((ext_vector_type(8)));
typedef float  f32x4  __attribute__((ext_vector_type(4)));
typedef u16    u16x8  __attribute__((ext_vector_type(8)));

__device__ __forceinline__ float bf2f(u16 u) {
    return __uint_as_float(((unsigned)u) << 16);
}
__device__ __forceinline__ u16 f2bf(float f) {   // round-to-nearest-even
    unsigned u = __float_as_uint(f);
    u += 0x7fffu + ((u >> 16) & 1u);
    return (u16)(u >> 16);
}
__device__ __forceinline__ u16x8 maxu16(u16x8 a, u16x8 b) {
    u16x8 r;
    #pragma unroll
    for (int e = 0; e < 8; ++e) r[e] = a[e] > b[e] ? a[e] : b[e];
    return r;
}
__device__ __forceinline__ void gload16(const u16* gp, u16* lp) {
    // async global->LDS, 16B/lane; LDS dest = wave-uniform base + lane*16
    __builtin_amdgcn_global_load_lds(
        (const __attribute__((address_space(1))) unsigned int*)gp,
        (__attribute__((address_space(3))) unsigned int*)lp, 16, 0, 0);
}

#define MFMA16(a, b, c) __builtin_amdgcn_mfma_f32_16x16x32_bf16(a, b, c, 0, 0, 0)

// Static device buffers — no d_ws dependency.
__device__ u16   h2g_buf[262144 * 64];            // h2 [N][64] bf16 (33.5 MB)
__device__ u16   hc_buf[(size_t)262144 * 192];    // [gm | h4] [N][192] (100.7 MB)
__device__ u16   w3b[64 * 64];                    // bf16 weights
__device__ u16   w4b[128 * 64];
__device__ u16   w5b[1024 * 192];
__device__ float g_buf[1024];                     // global column max (>= 0)
__device__ float f1_buf[512];
__device__ float f2_buf[256];

// ---------------------------------------------------------------------------
__global__ void k0_zero() { g_buf[threadIdx.x] = 0.f; }

__global__ void kcvt(const float* __restrict__ w3f, const float* __restrict__ w4f,
                     const float* __restrict__ w5f)
{
    int i = blockIdx.x * 256 + threadIdx.x;
    if (i < 4096)        w3b[i]         = f2bf(w3f[i]);
    else if (i < 12288)  w4b[i - 4096]  = f2bf(w4f[i - 4096]);
    else                 w5b[i - 12288] = f2bf(w5f[i - 12288]);
}

// ---------------------------------------------------------------------------
// k1: mlp1..mlp4 for 64 points/block.  h1 (VALU, K=3) -> h2 (MFMA, -> h2g_buf)
//     -> h3 (MFMA, b-frags direct from w3b) -> h4 (-> hc_buf cols 64..191).
//     Wave w owns rows 16w..16w+15 throughout (no inter-layer barriers).
// ---------------------------------------------------------------------------
__global__ __launch_bounds__(256) void k1_mlp(
    const float* __restrict__ xf, const float* __restrict__ w1f,
    const float* __restrict__ w2f)
{
    __shared__ __align__(16) u16 sw1[64 * 4];
    __shared__ __align__(16) u16 sx [64 * 4];
    __shared__ __align__(16) u16 sw2[64 * 72];
    __shared__ __align__(16) u16 shA[64 * 72];    // h1, then h3
    __shared__ __align__(16) u16 sh2[64 * 72];
    __shared__ __align__(16) u16 sh4[64 * 136];

    const int tid = threadIdx.x;
    const int p0  = blockIdx.x * 64;

    for (int i = tid; i < 64 * 64; i += 256)
        sw2[(i >> 6) * 72 + (i & 63)] = f2bf(w2f[i]);
    if (tid < 192) {
        sw1[(tid / 3) * 4 + tid % 3] = f2bf(w1f[tid]);
        sx [(tid / 3) * 4 + tid % 3] = f2bf(xf[p0 * 3 + tid]);
    }
    __syncthreads();

    {   // L1 via VALU (K=3)
        int m = tid & 63, ng = tid >> 6;
        float x0 = bf2f(sx[m * 4]), x1 = bf2f(sx[m * 4 + 1]), x2 = bf2f(sx[m * 4 + 2]);
        #pragma unroll
        for (int j = 0; j < 16; ++j) {
            int n = ng * 16 + j;
            float s = x0 * bf2f(sw1[n * 4]) + x1 * bf2f(sw1[n * 4 + 1]) + x2 * bf2f(sw1[n * 4 + 2]);
            shA[m * 72 + n] = f2bf(fmaxf(s, 0.f));
        }
    }
    __syncthreads();

    const int lane = tid & 63, w = tid >> 6, q = lane >> 4, l15 = lane & 15;
    const int mrow = 16 * w;

    // ---- L2: h2 = relu(h1@w2^T) -> sh2 ----
    {
        f32x4 acc[4];
        #pragma unroll
        for (int nt = 0; nt < 4; ++nt) acc[nt] = (f32x4){0.f, 0.f, 0.f, 0.f};
        #pragma unroll
        for (int ss = 0; ss < 2; ++ss) {
            bf16x8 a = *(const bf16x8*)&shA[(mrow + l15) * 72 + ss * 32 + q * 8];
            #pragma unroll
            for (int nt = 0; nt < 4; ++nt) {
                bf16x8 b = *(const bf16x8*)&sw2[(nt * 16 + l15) * 72 + ss * 32 + q * 8];
                acc[nt] = MFMA16(a, b, acc[nt]);
            }
        }
        #pragma unroll
        for (int nt = 0; nt < 4; ++nt)
            #pragma unroll
            for (int r = 0; r < 4; ++r)
                sh2[(mrow + q * 4 + r) * 72 + nt * 16 + l15] = f2bf(fmaxf(acc[nt][r], 0.f));
    }

    // ---- L3: h3 = relu(h2@w3^T) -> shA (wave-local rows, b from w3b) ----
    {
        f32x4 acc[4];
        #pragma unroll
        for (int nt = 0; nt < 4; ++nt) acc[nt] = (f32x4){0.f, 0.f, 0.f, 0.f};
        #pragma unroll
        for (int ss = 0; ss < 2; ++ss) {
            bf16x8 a = *(const bf16x8*)&sh2[(mrow + l15) * 72 + ss * 32 + q * 8];
            #pragma unroll
            for (int nt = 0; nt < 4; ++nt) {
                bf16x8 b = *(const bf16x8*)&w3b[(nt * 16 + l15) * 64 + ss * 32 + q * 8];
                acc[nt] = MFMA16(a, b, acc[nt]);
            }
        }
        #pragma unroll
        for (int nt = 0; nt < 4; ++nt)
            #pragma unroll
            for (int r = 0; r < 4; ++r)
                shA[(mrow + q * 4 + r) * 72 + nt * 16 + l15] = f2bf(fmaxf(acc[nt][r], 0.f));
    }

    // ---- L4: h4 = relu(h3@w4^T) -> sh4 (b from w4b) ----
    {
        f32x4 acc[8];
        #pragma unroll
        for (int nt = 0; nt < 8; ++nt) acc[nt] = (f32x4){0.f, 0.f, 0.f, 0.f};
        #pragma unroll
        for (int ss = 0; ss < 2; ++ss) {
            bf16x8 a = *(const bf16x8*)&shA[(mrow + l15) * 72 + ss * 32 + q * 8];
            #pragma unroll
            for (int nt = 0; nt < 8; ++nt) {
                bf16x8 b = *(const bf16x8*)&w4b[(nt * 16 + l15) * 64 + ss * 32 + q * 8];
                acc[nt] = MFMA16(a, b, acc[nt]);
            }
        }
        #pragma unroll
        for (int nt = 0; nt < 8; ++nt)
            #pragma unroll
            for (int r = 0; r < 4; ++r)
                sh4[(mrow + q * 4 + r) * 136 + nt * 16 + l15] = f2bf(fmaxf(acc[nt][r], 0.f));
    }
    __syncthreads();

    // ---- cooperative vectorized stores: h2 -> h2g_buf, h4 -> hc[:,64:192] ----
    {
        int row = tid >> 2, c = (tid & 3) * 16;
        *(u16x8*)&h2g_buf[(size_t)p0 * 64 + tid * 16]     = *(const u16x8*)&sh2[row * 72 + c];
        *(u16x8*)&h2g_buf[(size_t)p0 * 64 + tid * 16 + 8] = *(const u16x8*)&sh2[row * 72 + c + 8];
        int cc = (tid & 3) * 32;
        #pragma unroll
        for (int i = 0; i < 4; ++i)
            *(u16x8*)&hc_buf[(size_t)(p0 + row) * 192 + 64 + cc + i * 8] =
                *(const u16x8*)&sh4[row * 136 + cc + i * 8];
    }
}

// ---------------------------------------------------------------------------
// k2_pool: 8 threads per point (16B channel chunk each). 16 independent
//   row-gathers in flight, packed-u16 max (valid: post-relu bf16 >= 0),
//   writes hc[:,0:64]. Lanes 0..7 of each group read consecutive 16B of the
//   same row -> each wave-load = 8 fully-coalesced 128B segments.
// ---------------------------------------------------------------------------
__global__ __launch_bounds__(256) void k2_pool(const int* __restrict__ idx)
{
    const size_t gt = (size_t)blockIdx.x * 256 + threadIdx.x;
    const size_t p  = gt >> 3;
    const int    c  = (threadIdx.x & 7) * 8;

    u16x8 v[16];
    #pragma unroll
    for (int k = 0; k < 16; ++k) {
        int j = idx[p * 16 + k];
        v[k] = *(const u16x8*)&h2g_buf[(size_t)j * 64 + c];
    }
    u16x8 m = v[0];
    #pragma unroll
    for (int k = 1; k < 16; ++k) m = maxu16(m, v[k]);
    *(u16x8*)&hc_buf[p * 192 + c] = m;
}

// ---------------------------------------------------------------------------
// k3_gemm: m97-style. One block = one (m-tile 128, bn 128-col) pair; 3 kt
//   stages of BK=64 staged via global_load_lds width=16 (chunk-major 8-row
//   LDS groups -> conflict-free ds_read_b128 frags). LDS 32KB -> ~5 blk/CU.
//   Grid swizzle keeps each m-tile's 8 bn-blocks on one XCD (A L2-resident).
//   Epilogue: relu folded into 0-init column max -> atomicMax (relu >= 0).
//   LDS addr (row r, chunk c): (r&~7)*64 + c*64 + (r&7)*8  [u16 units]
// ---------------------------------------------------------------------------
__global__ __launch_bounds__(256) void k3_gemm(int* __restrict__ g)
{
    __shared__ __align__(16) u16 sA[128 * 64];   // 16 KB
    __shared__ __align__(16) u16 sB[128 * 64];   // 16 KB

    const int tid  = threadIdx.x;
    const int lane = tid & 63, w = tid >> 6, q = lane >> 4, l15 = lane & 15;
    const int m0w  = (w & 1) * 64, n0w = (w >> 1) * 64;

    const int i   = blockIdx.x;
    const int mt_ = ((i & 7) << 8) | (i >> 6);   // m-tile 0..2047 (XCD-local)
    const int bn  = (i >> 3) & 7;

    const size_t Ar0 = (size_t)mt_ * 128;
    const size_t Br0 = (size_t)bn * 128;
    const int lr = lane & 7, lc = lane >> 3;     // staging row-in-8 / chunk

    f32x4 acc[4][4];
    #pragma unroll
    for (int mt = 0; mt < 4; ++mt)
        #pragma unroll
        for (int nt = 0; nt < 4; ++nt) acc[mt][nt] = (f32x4){0.f, 0.f, 0.f, 0.f};

    for (int kt = 0; kt < 3; ++kt) {
        if (kt) __syncthreads();                 // prior-stage LDS reads done
        #pragma unroll
        for (int c = 0; c < 4; ++c) {
            int r0 = 32 * w + 8 * c;             // wave stages rows r0..r0+7 per call
            gload16(&hc_buf[(Ar0 + r0 + lr) * 192 + kt * 64 + lc * 8], &sA[r0 * 64]);
            gload16(&w5b  [(Br0 + r0 + lr) * 192 + kt * 64 + lc * 8], &sB[r0 * 64]);
        }
        __syncthreads();                         // drains vmcnt (compiler)
        #pragma unroll
        for (int ss = 0; ss < 2; ++ss) {
            const int c = ss * 4 + q;
            bf16x8 a[4], b[4];
            #pragma unroll
            for (int mt = 0; mt < 4; ++mt) {
                int m = m0w + mt * 16 + l15;
                a[mt] = *(const bf16x8*)&sA[(m & ~7) * 64 + c * 64 + (m & 7) * 8];
            }
            #pragma unroll
            for (int nt = 0; nt < 4; ++nt) {
                int n = n0w + nt * 16 + l15;
                b[nt] = *(const bf16x8*)&sB[(n & ~7) * 64 + c * 64 + (n & 7) * 8];
            }
            #pragma unroll
            for (int mt = 0; mt < 4; ++mt)
                #pragma unroll
                for (int nt = 0; nt < 4; ++nt)
                    acc[mt][nt] = MFMA16(a[mt], b[nt], acc[mt][nt]);
        }
    }

    #pragma unroll
    for (int nt = 0; nt < 4; ++nt) {
        float mx = 0.f;                          // relu folded into 0-init
        #pragma unroll
        for (int mt = 0; mt < 4; ++mt)
            #pragma unroll
            for (int r = 0; r < 4; ++r) mx = fmaxf(mx, acc[mt][nt][r]);
        mx = fmaxf(mx, __shfl_xor(mx, 16, 64));
        mx = fmaxf(mx, __shfl_xor(mx, 32, 64));
        if (q == 0) {
            int col = bn * 128 + n0w + nt * 16 + l15;
            atomicMax(&g[col], __float_as_int(mx));
        }
    }
}

// ---------------------------------------------------------------------------
// k4: classifier head, pure f32. One wave per output row.
// ---------------------------------------------------------------------------
__global__ void k4_f1(const float* __restrict__ wf1)
{
    int r = blockIdx.x, l = threadIdx.x;
    float s = 0.f;
    #pragma unroll
    for (int i = 0; i < 16; ++i) s += wf1[r * 1024 + i * 64 + l] * g_buf[i * 64 + l];
    #pragma unroll
    for (int o = 32; o; o >>= 1) s += __shfl_down(s, o, 64);
    if (!l) f1_buf[r] = fmaxf(s, 0.f);
}
__global__ void k4_f2(const float* __restrict__ wf2)
{
    int r = blockIdx.x, l = threadIdx.x;
    float s = 0.f;
    #pragma unroll
    for (int i = 0; i < 8; ++i) s += wf2[r * 512 + i * 64 + l] * f1_buf[i * 64 + l];
    #pragma unroll
    for (int o = 32; o; o >>= 1) s += __shfl_down(s, o, 64);
    if (!l) f2_buf[r] = fmaxf(s, 0.f);
}
__global__ void k4_out(const float* __restrict__ wf3, float* __restrict__ out)
{
    int r = blockIdx.x, l = threadIdx.x;
    float s = 0.f;
    #pragma unroll
    for (int i = 0; i < 4; ++i) s += wf3[r * 256 + i * 64 + l] * f2_buf[i * 64 + l];
    #pragma unroll
    for (int o = 32; o; o >>= 1) s += __shfl_down(s, o, 64);
    if (!l) out[r] = s;
}

// ---------------------------------------------------------------------------
extern "C" void kernel_launch(void* const* d_in, const int* in_sizes, int n_in,
                              void* d_out, int out_size, void* d_ws, size_t ws_size,
                              hipStream_t stream)
{
    (void)in_sizes; (void)n_in; (void)out_size; (void)d_ws; (void)ws_size;
    const float* x   = (const float*)d_in[0];
    const int*   idx = (const int*)d_in[2];
    const float* w1  = (const float*)d_in[3];
    const float* w2  = (const float*)d_in[4];
    const float* w3  = (const float*)d_in[5];
    const float* w4  = (const float*)d_in[6];
    const float* w5  = (const float*)d_in[7];
    const float* wf1 = (const float*)d_in[8];
    const float* wf2 = (const float*)d_in[9];
    const float* wf3 = (const float*)d_in[10];

    float* gptr;
    hipGetSymbolAddress((void**)&gptr, HIP_SYMBOL(g_buf));

    k0_zero<<<1, 1024, 0, stream>>>();
    kcvt   <<<816, 256, 0, stream>>>(w3, w4, w5);
    k1_mlp <<<262144 / 64, 256, 0, stream>>>(x, w1, w2);
    k2_pool<<<262144 * 8 / 256, 256, 0, stream>>>(idx);
    k3_gemm<<<16384, 256, 0, stream>>>((int*)gptr);
    k4_f1  <<<512, 64, 0, stream>>>(wf1);
    k4_f2  <<<256, 64, 0, stream>>>(wf2);
    k4_out <<<40, 64, 0, stream>>>(wf3, (float*)d_out);
}